// Round 6
// baseline (598.140 us; speedup 1.0000x reference)
//
#include <hip/hip_runtime.h>
#include <hip/hip_bf16.h>

typedef unsigned int u32;
typedef unsigned short u16;

using bf16x8 = __attribute__((ext_vector_type(8))) short;
using f32x4  = __attribute__((ext_vector_type(4))) float;

#define DEVI static __device__ __forceinline__

DEVI u16 f2bf(float f) {
  __hip_bfloat16 h = __float2bfloat16(f);  // RNE
  union { __hip_bfloat16 h; u16 u; } v; v.h = h;
  return v.u;
}

// ---------------------------------------------------------------------------
// Kernel 1: select + convert x[:, :2048, :] (f32) -> Xb bf16 [8192][2048]
// Router is identity: softmax over size-1 axis == 1.0; top_k of equal scores
// returns indices 0..2047 (stable tie-break).
// ---------------------------------------------------------------------------
__global__ void k_convert_x(const float* __restrict__ x, u16* __restrict__ xb) {
  int idx = blockIdx.x * blockDim.x + threadIdx.x;   // 4 elems per thread
  size_t e = (size_t)idx * 4;
  int row = (int)(e >> 11);        // 0..8191
  int d   = (int)(e & 2047);
  int b = row >> 11, t = row & 2047;
  const float4 v = *reinterpret_cast<const float4*>(
      x + ((size_t)(b * 4096 + t) * 2048 + d));
  ushort4 o;
  o.x = f2bf(v.x); o.y = f2bf(v.y); o.z = f2bf(v.z); o.w = f2bf(v.w);
  *reinterpret_cast<ushort4*>(xb + (size_t)row * 2048 + d) = o;
}

// ---------------------------------------------------------------------------
// Kernel 2: transpose + convert  in[R][C] f32  ->  out[C][R] bf16
// ---------------------------------------------------------------------------
__global__ void k_transpose_bf16(const float* __restrict__ in,
                                 u16* __restrict__ out, int R, int C) {
  __shared__ u16 lds[64][66];
  const int t = threadIdx.x;        // 256
  const int tile_r = blockIdx.y * 64;
  const int tile_c = blockIdx.x * 64;
  const int cc = (t & 15) * 4;
  const int r0 = t >> 4;
#pragma unroll
  for (int i = 0; i < 4; ++i) {
    int r = r0 + i * 16;
    const float4 v = *reinterpret_cast<const float4*>(
        in + (size_t)(tile_r + r) * C + tile_c + cc);
    lds[r][cc]     = f2bf(v.x);
    lds[r][cc + 1] = f2bf(v.y);
    lds[r][cc + 2] = f2bf(v.z);
    lds[r][cc + 3] = f2bf(v.w);
  }
  __syncthreads();
  const int rr = (t & 15) * 4;
  const int c0 = t >> 4;
#pragma unroll
  for (int i = 0; i < 4; ++i) {
    int c = c0 + i * 16;
    ushort4 o;
    o.x = lds[rr][c]; o.y = lds[rr + 1][c];
    o.z = lds[rr + 2][c]; o.w = lds[rr + 3][c];
    *reinterpret_cast<ushort4*>(out + (size_t)(tile_c + c) * R + tile_r + rr) = o;
  }
}

// ---------------------------------------------------------------------------
// Kernel 3: 256x256 bf16 GEMM (16x16x32), schedule v3:
//   4 phases / K-tile, 8 barriers, no boundary phase.
//   ph0: stage kt+1 pairs 0,1 | q00 (0 reads)
//   ph1: read b1 (4)  | stage kt+1 pairs 2,3 | q01
//   ph2: read aH (8)  | q11
//   ph3: vmcnt(0) [all loads >=2 phases old -> free] | barrier publishes
//        next buf | q10 | 12 lookahead reads (aL', b0' for kt+1) drain
//        under other waves' q10.
//   T2 swizzle (phys = logical ^ ((row&7)<<4), both-sides involution),
//   T5 setprio, XCD-bijective block swizzle. Measured 0 bank conflicts.
// ---------------------------------------------------------------------------
#define GLDS16(g, l)                                                          \
  __builtin_amdgcn_global_load_lds(                                           \
      (const __attribute__((address_space(1))) u32*)(g),                      \
      (__attribute__((address_space(3))) u32*)(l), 16, 0, 0)

#define MFMA_GATE()                                                           \
  do {                                                                        \
    asm volatile("s_waitcnt lgkmcnt(0)" ::: "memory");                        \
    __builtin_amdgcn_sched_barrier(0);                                        \
  } while (0)

template <int DO_GELU>
__global__ __launch_bounds__(512, 2) void k_gemm8(
    const u16* __restrict__ A, const u16* __restrict__ B,
    const float* __restrict__ bias, void* __restrict__ Cout,
    int M, int N, int K, int nbn) {
  // u16 units: [0..16383] A p=0 | A p=1 | [32768..] B p=0 | B p=1
  __shared__ __align__(64) u16 lds[65536];

  // XCD-aware bijective swizzle (grid % 8 == 0 for both launches)
  const int nwg = gridDim.x;
  const int bid = blockIdx.x;
  const int wg  = (bid & 7) * (nwg >> 3) + (bid >> 3);
  const int bm = wg / nbn, bn = wg % nbn;

  const int tid  = threadIdx.x;
  const int w    = tid >> 6, lane = tid & 63;
  const int wr   = w >> 2, wcol = w & 3;   // wave tile: rows wr*128, cols wcol*64
  const int l15  = lane & 15, lhi = lane >> 4;

  const size_t arow0 = (size_t)bm * 256;
  const size_t brow0 = (size_t)bn * 256;

  // ---- staging: lane covers phys 16B chunk -> logical col chunk is XOR'd
  const int srow  = tid >> 3;                                  // 0..63
  const int scolb = ((tid & 7) * 16) ^ ((srow & 7) << 4);      // byte col in row
  const u16* pA = A + (arow0 + srow) * (size_t)K + (scolb >> 1);
  const u16* pB = B + (brow0 + srow) * (size_t)K + (scolb >> 1);
  const int wA = w * 512;  // u16 offset of this wave's 1KB stage slot

  // ---- fragment-read bases (bytes), swizzle folded in
  const u32 arow_b = (u32)((wr * 128 + l15) * 128);
  const u32 brow_b = (u32)((wcol * 64 + l15) * 128);
  const u32 axor   = (u32)((lhi * 16) ^ ((l15 & 7) << 4));
  const char* ldsb = (const char*)lds;

  f32x4 acc[8][4] = {};
  const int nk = K >> 6;

#define STAGE_PAIR(KT, PB, C)                                                 \
  do {                                                                        \
    GLDS16(pA + (size_t)(KT) * 64 + (size_t)(C) * 64 * (size_t)K,             \
           lds + (PB) * 16384 + (C) * 4096 + wA);                             \
    GLDS16(pB + (size_t)(KT) * 64 + (size_t)(C) * 64 * (size_t)K,             \
           lds + 32768 + (PB) * 16384 + (C) * 4096 + wA);                     \
  } while (0)

#define READ_A(DST, MH, ABASE)                                                \
  _Pragma("unroll") for (int m2 = 0; m2 < 4; ++m2)                            \
  _Pragma("unroll") for (int kk = 0; kk < 2; ++kk)                            \
    DST[m2][kk] = *(const bf16x8*)(ldsb + (ABASE) + arow_b +                  \
                                   ((MH)*4 + m2) * 2048 + (axor ^ (kk << 6)));

#define READ_B(DST, NH, BBASE)                                                \
  _Pragma("unroll") for (int n2 = 0; n2 < 2; ++n2)                            \
  _Pragma("unroll") for (int kk = 0; kk < 2; ++kk)                            \
    DST[n2][kk] = *(const bf16x8*)(ldsb + (BBASE) + brow_b +                  \
                                   ((NH)*2 + n2) * 2048 + (axor ^ (kk << 6)));

#define MFMA_Q(MH, NH, AREG, BREG)                                            \
  _Pragma("unroll") for (int m2 = 0; m2 < 4; ++m2)                            \
  _Pragma("unroll") for (int n2 = 0; n2 < 2; ++n2)                            \
  _Pragma("unroll") for (int kk = 0; kk < 2; ++kk)                            \
    acc[(MH)*4 + m2][(NH)*2 + n2] = __builtin_amdgcn_mfma_f32_16x16x32_bf16(  \
        AREG[m2][kk], BREG[n2][kk], acc[(MH)*4 + m2][(NH)*2 + n2], 0, 0, 0);

  bf16x8 aL[4][2], aH[4][2], b0[2][2], b1[2][2];

  // ---- prologue: stage kt0 fully, publish buf0, preload aL/b0 for kt0.
  STAGE_PAIR(0, 0, 0); STAGE_PAIR(0, 0, 1);
  STAGE_PAIR(0, 0, 2); STAGE_PAIR(0, 0, 3);
  asm volatile("s_waitcnt vmcnt(0)" ::: "memory");
  __builtin_amdgcn_s_barrier();
  __builtin_amdgcn_sched_barrier(0);
  READ_A(aL, 0, 0u);
  READ_B(b0, 0, 65536u);

  for (int kt = 0; kt < nk; ++kt) {
    const int p = kt & 1;
    const u32 abase  = (u32)p * 32768u;             // current bufs (bytes)
    const u32 bbase  = 65536u + (u32)p * 32768u;
    const u32 nabase = (u32)(p ^ 1) * 32768u;       // next bufs
    const u32 nbbase = 65536u + (u32)(p ^ 1) * 32768u;

    // ph0: stage kt+1 pairs 0,1 ; q00 = aL x b0 (reads done last ph3)
    if (kt + 1 < nk) { STAGE_PAIR(kt + 1, p ^ 1, 0); STAGE_PAIR(kt + 1, p ^ 1, 1); }
    __builtin_amdgcn_s_barrier();
    MFMA_GATE();
    __builtin_amdgcn_s_setprio(1);
    MFMA_Q(0, 0, aL, b0);
    __builtin_amdgcn_s_setprio(0);
    __builtin_amdgcn_s_barrier();

    // ph1: read b1 (4) ; stage kt+1 pairs 2,3 ; q01 = aL x b1
    READ_B(b1, 1, bbase);
    if (kt + 1 < nk) { STAGE_PAIR(kt + 1, p ^ 1, 2); STAGE_PAIR(kt + 1, p ^ 1, 3); }
    __builtin_amdgcn_s_barrier();
    MFMA_GATE();
    __builtin_amdgcn_s_setprio(1);
    MFMA_Q(0, 1, aL, b1);
    __builtin_amdgcn_s_setprio(0);
    __builtin_amdgcn_s_barrier();

    // ph2: read aH (8) ; q11 = aH x b1
    READ_A(aH, 1, abase);
    __builtin_amdgcn_s_barrier();
    MFMA_GATE();
    __builtin_amdgcn_s_setprio(1);
    MFMA_Q(1, 1, aH, b1);
    __builtin_amdgcn_s_setprio(0);
    __builtin_amdgcn_s_barrier();

    // ph3: publish next buf (vmcnt free: loads >=2 phases old) ; q10 ;
    //      lookahead reads for kt+1 drain under other waves' q10.
    asm volatile("s_waitcnt vmcnt(0)" ::: "memory");
    __builtin_amdgcn_s_barrier();
    __builtin_amdgcn_sched_barrier(0);
    __builtin_amdgcn_s_setprio(1);
    MFMA_Q(1, 0, aH, b0);
    __builtin_amdgcn_s_setprio(0);
    if (kt + 1 < nk) {
      READ_A(aL, 0, nabase);   // WAR on b0/aL ordered by register deps
      READ_B(b0, 0, nbbase);
    }
    __builtin_amdgcn_s_barrier();
  }

  // ---- epilogue: C/D layout col = lane&15, row = (lane>>4)*4 + reg
#pragma unroll
  for (int m = 0; m < 8; ++m) {
    const int row = (int)arow0 + wr * 128 + m * 16 + lhi * 4;
#pragma unroll
    for (int n = 0; n < 4; ++n) {
      const int col = (int)brow0 + wcol * 64 + n * 16 + l15;
      const float bb = bias[col];
#pragma unroll
      for (int r = 0; r < 4; ++r) {
        float v = acc[m][n][r] + bb;
        if (DO_GELU) {
          float u2 = v * (1.5957691216f + 0.0713548162f * v * v);
          float g  = v / (1.f + __expf(-u2));
          ((u16*)Cout)[(size_t)(row + r) * N + col] = f2bf(g);
        } else {
          ((float*)Cout)[(size_t)(row + r) * N + col] = v;
        }
      }
    }
  }
#undef STAGE_PAIR
#undef READ_A
#undef READ_B
#undef MFMA_Q
}

// ---------------------------------------------------------------------------
extern "C" void kernel_launch(void* const* d_in, const int* in_sizes, int n_in,
                              void* d_out, int out_size, void* d_ws,
                              size_t ws_size, hipStream_t stream) {
  const float* x  = (const float*)d_in[0];
  // d_in[1] = Wp, d_in[2] = bp : router is identity, unused.
  const float* W1 = (const float*)d_in[3];
  const float* b1 = (const float*)d_in[4];
  const float* W2 = (const float*)d_in[5];
  const float* b2 = (const float*)d_in[6];
  float* out = (float*)d_out;

  char* ws = (char*)d_ws;
  u16* Xb  = (u16*)(ws);                       // 8192x2048 bf16 = 32 MiB
  u16* W1T = (u16*)(ws + 33554432);            // 8192x2048 bf16 = 32 MiB
  u16* W2T = (u16*)(ws + 67108864);            // 2048x8192 bf16 = 32 MiB
  u16* H   = (u16*)(ws + 100663296);           // 8192x8192 bf16 = 128 MiB

  // 1. select + convert x
  k_convert_x<<<16384, 256, 0, stream>>>(x, Xb);
  // 2. transpose-convert weights
  k_transpose_bf16<<<dim3(8192 / 64, 2048 / 64), 256, 0, stream>>>(W1, W1T, 2048, 8192);
  k_transpose_bf16<<<dim3(2048 / 64, 8192 / 64), 256, 0, stream>>>(W2, W2T, 8192, 2048);
  // 3. H = gelu(Xb @ W1 + b1) : M=8192 N=8192 K=2048, 32x32 = 1024 blocks
  k_gemm8<1><<<1024, 512, 0, stream>>>(Xb, W1T, b1, (void*)H, 8192, 8192, 2048, 32);
  // 4. out = H @ W2 + b2      : M=8192 N=2048 K=8192, 32x8 = 256 blocks
  k_gemm8<0><<<256, 512, 0, stream>>>(H, W2T, b2, (void*)out, 8192, 2048, 8192, 8);
}

// Round 7
// 575.562 us; speedup vs baseline: 1.0392x; 1.0392x over previous
//
#include <hip/hip_runtime.h>
#include <hip/hip_bf16.h>

typedef unsigned int u32;
typedef unsigned short u16;

using bf16x8 = __attribute__((ext_vector_type(8))) short;
using f32x4  = __attribute__((ext_vector_type(4))) float;

#define DEVI static __device__ __forceinline__

DEVI u16 f2bf(float f) {
  __hip_bfloat16 h = __float2bfloat16(f);  // RNE
  union { __hip_bfloat16 h; u16 u; } v; v.h = h;
  return v.u;
}

// ---------------------------------------------------------------------------
// Kernel 1: select + convert x[:, :2048, :] (f32) -> Xb bf16 [8192][2048]
// Router is identity: softmax over size-1 axis == 1.0; top_k of equal scores
// returns indices 0..2047 (stable tie-break).
// ---------------------------------------------------------------------------
__global__ void k_convert_x(const float* __restrict__ x, u16* __restrict__ xb) {
  int idx = blockIdx.x * blockDim.x + threadIdx.x;   // 4 elems per thread
  size_t e = (size_t)idx * 4;
  int row = (int)(e >> 11);        // 0..8191
  int d   = (int)(e & 2047);
  int b = row >> 11, t = row & 2047;
  const float4 v = *reinterpret_cast<const float4*>(
      x + ((size_t)(b * 4096 + t) * 2048 + d));
  ushort4 o;
  o.x = f2bf(v.x); o.y = f2bf(v.y); o.z = f2bf(v.z); o.w = f2bf(v.w);
  *reinterpret_cast<ushort4*>(xb + (size_t)row * 2048 + d) = o;
}

// ---------------------------------------------------------------------------
// Kernel 2: transpose + convert  in[R][C] f32  ->  out[C][R] bf16
// ---------------------------------------------------------------------------
__global__ void k_transpose_bf16(const float* __restrict__ in,
                                 u16* __restrict__ out, int R, int C) {
  __shared__ u16 lds[64][66];
  const int t = threadIdx.x;        // 256
  const int tile_r = blockIdx.y * 64;
  const int tile_c = blockIdx.x * 64;
  const int cc = (t & 15) * 4;
  const int r0 = t >> 4;
#pragma unroll
  for (int i = 0; i < 4; ++i) {
    int r = r0 + i * 16;
    const float4 v = *reinterpret_cast<const float4*>(
        in + (size_t)(tile_r + r) * C + tile_c + cc);
    lds[r][cc]     = f2bf(v.x);
    lds[r][cc + 1] = f2bf(v.y);
    lds[r][cc + 2] = f2bf(v.z);
    lds[r][cc + 3] = f2bf(v.w);
  }
  __syncthreads();
  const int rr = (t & 15) * 4;
  const int c0 = t >> 4;
#pragma unroll
  for (int i = 0; i < 4; ++i) {
    int c = c0 + i * 16;
    ushort4 o;
    o.x = lds[rr][c]; o.y = lds[rr + 1][c];
    o.z = lds[rr + 2][c]; o.w = lds[rr + 3][c];
    *reinterpret_cast<ushort4*>(out + (size_t)(tile_c + c) * R + tile_r + rr) = o;
  }
}

// ---------------------------------------------------------------------------
// Kernel 3: 256x256 bf16 GEMM (16x16x32), R1 schedule (best measured):
//   4 phases + boundary, counted vmcnt(4), T5 setprio, T2 XOR swizzle
//   (phys = logical ^ ((row&7)<<4), both-sides involution; 0 conflicts).
//   NEW: bn-partitioned XCD mapping (XCD owns nbn/8 B-columns -> per-XCD
//   B working set <= 4 MB, L2-resident) and LDS-bounce coalesced epilogue.
// ---------------------------------------------------------------------------
#define GLDS16(g, l)                                                          \
  __builtin_amdgcn_global_load_lds(                                           \
      (const __attribute__((address_space(1))) u32*)(g),                      \
      (__attribute__((address_space(3))) u32*)(l), 16, 0, 0)

template <int DO_GELU>
DEVI void gemm_body(u16* lds, const u16* __restrict__ A,
                    const u16* __restrict__ B, const float* __restrict__ bias,
                    void* __restrict__ Cout, int M, int N, int K, int sft) {
  // XCD bn-partition mapping: xcd = bid&7 owns bn in [xcd<<sft, (xcd+1)<<sft)
  const int bid   = blockIdx.x;
  const int local = bid >> 3;
  const int bn    = ((bid & 7) << sft) + (local & ((1 << sft) - 1));
  const int bm    = local >> sft;

  const int tid  = threadIdx.x;
  const int w    = tid >> 6, lane = tid & 63;
  const int wr   = w >> 2, wcol = w & 3;   // wave tile: rows wr*128, cols wcol*64
  const int l15  = lane & 15, lhi = lane >> 4;

  const size_t arow0 = (size_t)bm * 256;
  const size_t brow0 = (size_t)bn * 256;

  // ---- staging: lane covers phys 16B chunk -> logical col chunk is XOR'd
  const int srow  = tid >> 3;                                  // 0..63
  const int scolb = ((tid & 7) * 16) ^ ((srow & 7) << 4);      // byte col in row
  const u16* pA = A + (arow0 + srow) * (size_t)K + (scolb >> 1);
  const u16* pB = B + (brow0 + srow) * (size_t)K + (scolb >> 1);
  const int wA = w * 512;  // u16 offset of this wave's 1KB stage slot

  // ---- fragment-read bases (bytes), swizzle folded in
  const u32 arow_b = (u32)((wr * 128 + l15) * 128);
  const u32 brow_b = (u32)((wcol * 64 + l15) * 128);
  const u32 axor   = (u32)((lhi * 16) ^ ((l15 & 7) << 4));
  const char* ldsb = (const char*)lds;

  f32x4 acc[8][4] = {};
  const int nk = K >> 6;

#define STAGE_PAIR(KT, PB, C)                                                 \
  do {                                                                        \
    GLDS16(pA + (size_t)(KT) * 64 + (size_t)(C) * 64 * (size_t)K,             \
           lds + (PB) * 16384 + (C) * 4096 + wA);                             \
    GLDS16(pB + (size_t)(KT) * 64 + (size_t)(C) * 64 * (size_t)K,             \
           lds + 32768 + (PB) * 16384 + (C) * 4096 + wA);                     \
  } while (0)

#define READ_A(MH, ABASE)                                                     \
  _Pragma("unroll") for (int m2 = 0; m2 < 4; ++m2)                            \
  _Pragma("unroll") for (int kk = 0; kk < 2; ++kk)                            \
    afr[m2][kk] = *(const bf16x8*)(ldsb + (ABASE) + arow_b +                  \
                                   ((MH)*4 + m2) * 2048 + (axor ^ (kk << 6)));

#define READ_B(DST, NH, BBASE)                                                \
  _Pragma("unroll") for (int n2 = 0; n2 < 2; ++n2)                            \
  _Pragma("unroll") for (int kk = 0; kk < 2; ++kk)                            \
    DST[n2][kk] = *(const bf16x8*)(ldsb + (BBASE) + brow_b +                  \
                                   ((NH)*2 + n2) * 2048 + (axor ^ (kk << 6)));

#define MFMA_Q(MH, NH, BREG)                                                  \
  _Pragma("unroll") for (int m2 = 0; m2 < 4; ++m2)                            \
  _Pragma("unroll") for (int n2 = 0; n2 < 2; ++n2)                            \
  _Pragma("unroll") for (int kk = 0; kk < 2; ++kk)                            \
    acc[(MH)*4 + m2][(NH)*2 + n2] = __builtin_amdgcn_mfma_f32_16x16x32_bf16(  \
        afr[m2][kk], BREG[n2][kk], acc[(MH)*4 + m2][(NH)*2 + n2], 0, 0, 0);

  // ---- prologue: kt0 fully, kt1 pairs 0,1 in flight.
  STAGE_PAIR(0, 0, 0); STAGE_PAIR(0, 0, 1);
  STAGE_PAIR(0, 0, 2); STAGE_PAIR(0, 0, 3);
  if (nk > 1) {
    STAGE_PAIR(1, 1, 0); STAGE_PAIR(1, 1, 1);
    asm volatile("s_waitcnt vmcnt(4)" ::: "memory");
  } else {
    asm volatile("s_waitcnt vmcnt(0)" ::: "memory");
  }
  __builtin_amdgcn_s_barrier();

  for (int kt = 0; kt < nk; ++kt) {
    const int p = kt & 1;
    const u32 abase = (u32)p * 32768u;            // bytes
    const u32 bbase = 65536u + (u32)p * 32768u;   // bytes
    bf16x8 afr[4][2], b0[2][2], b1[2][2];

    // phase 0: quadrant (mh0, nh0) — 12 reads
    READ_A(0, abase);
    READ_B(b0, 0, bbase);
    if (kt + 1 < nk) STAGE_PAIR(kt + 1, p ^ 1, 2);
    __builtin_amdgcn_s_barrier();
    __builtin_amdgcn_s_setprio(1);
    MFMA_Q(0, 0, b0);
    __builtin_amdgcn_s_setprio(0);
    __builtin_amdgcn_s_barrier();

    // phase 1: (mh0, nh1) — 4 reads
    READ_B(b1, 1, bbase);
    if (kt + 1 < nk) STAGE_PAIR(kt + 1, p ^ 1, 3);
    __builtin_amdgcn_s_barrier();
    __builtin_amdgcn_s_setprio(1);
    MFMA_Q(0, 1, b1);
    __builtin_amdgcn_s_setprio(0);
    __builtin_amdgcn_s_barrier();

    // phase 2: (mh1, nh1) — 8 reads, reuse b1
    READ_A(1, abase);
    __builtin_amdgcn_s_barrier();
    __builtin_amdgcn_s_setprio(1);
    MFMA_Q(1, 1, b1);
    __builtin_amdgcn_s_setprio(0);
    __builtin_amdgcn_s_barrier();

    // phase 3: (mh1, nh0) — 0 reads, reuse b0
    __builtin_amdgcn_s_setprio(1);
    MFMA_Q(1, 0, b0);
    __builtin_amdgcn_s_setprio(0);
    __builtin_amdgcn_s_barrier();

    // boundary: buf p dead; issue kt+2 pairs 0,1, wait kt+1's 8 loads done.
    if (kt + 2 < nk) {
      STAGE_PAIR(kt + 2, p, 0); STAGE_PAIR(kt + 2, p, 1);
      asm volatile("s_waitcnt vmcnt(4)" ::: "memory");
    } else {
      asm volatile("s_waitcnt vmcnt(0)" ::: "memory");
    }
    __builtin_amdgcn_s_barrier();
  }

  // ---- epilogue: LDS-bounce to coalesced stores.
  // C/D frag layout: col = lane&15 (within 16), row = (lane>>4)*4 + reg.
  // All waves are past the final barrier -> main-loop LDS is dead; each wave
  // uses a private slot, wave-local lgkmcnt(0) orders write->read.
  const int colb = (int)brow0 + wcol * 64;
  float bb[4];
#pragma unroll
  for (int n = 0; n < 4; ++n) bb[n] = bias[colb + n * 16 + l15];
  const int tr = lane >> 2, tc = (lane & 3) * 16;

  if (DO_GELU) {
    u16* slot = lds + (size_t)w * 1152;          // 16 x 72 u16 (144B rows)
#pragma unroll
    for (int m = 0; m < 8; ++m) {
      const int rowb = (int)arow0 + wr * 128 + m * 16;
#pragma unroll
      for (int n = 0; n < 4; ++n)
#pragma unroll
        for (int r = 0; r < 4; ++r) {
          float v = acc[m][n][r] + bb[n];
          float u2 = v * (1.5957691216f + 0.0713548162f * v * v);
          float g  = v / (1.f + __expf(-u2));
          slot[(lhi * 4 + r) * 72 + n * 16 + l15] = f2bf(g);
        }
      asm volatile("s_waitcnt lgkmcnt(0)" ::: "memory");
      uint4 d0 = *(const uint4*)(slot + tr * 72 + tc);
      uint4 d1 = *(const uint4*)(slot + tr * 72 + tc + 8);
      u16* gp = (u16*)Cout + (size_t)(rowb + tr) * N + colb + tc;
      *(uint4*)gp = d0;
      *(uint4*)(gp + 8) = d1;
      asm volatile("s_waitcnt lgkmcnt(0)" ::: "memory");  // reads done before next m overwrites
    }
  } else {
    float* slotf = (float*)(void*)lds + (size_t)w * 1088;  // 16 x 68 f32 (272B rows)
#pragma unroll
    for (int m = 0; m < 8; ++m) {
      const int rowb = (int)arow0 + wr * 128 + m * 16;
#pragma unroll
      for (int n = 0; n < 4; ++n)
#pragma unroll
        for (int r = 0; r < 4; ++r)
          slotf[(lhi * 4 + r) * 68 + n * 16 + l15] = acc[m][n][r] + bb[n];
      asm volatile("s_waitcnt lgkmcnt(0)" ::: "memory");
      float4 f0 = *(const float4*)(slotf + tr * 68 + tc);
      float4 f1 = *(const float4*)(slotf + tr * 68 + tc + 4);
      float4 f2 = *(const float4*)(slotf + tr * 68 + tc + 8);
      float4 f3 = *(const float4*)(slotf + tr * 68 + tc + 12);
      float* gp = (float*)Cout + (size_t)(rowb + tr) * N + colb + tc;
      *(float4*)gp = f0;
      *(float4*)(gp + 4) = f1;
      *(float4*)(gp + 8) = f2;
      *(float4*)(gp + 12) = f3;
      asm volatile("s_waitcnt lgkmcnt(0)" ::: "memory");
    }
  }
#undef STAGE_PAIR
#undef READ_A
#undef READ_B
#undef MFMA_Q
}

__global__ __launch_bounds__(512, 2) void k_ffn1(
    const u16* __restrict__ A, const u16* __restrict__ B,
    const float* __restrict__ bias, void* __restrict__ Cout,
    int M, int N, int K, int sft) {
  __shared__ __align__(64) u16 lds[65536];
  gemm_body<1>(lds, A, B, bias, Cout, M, N, K, sft);
}

__global__ __launch_bounds__(512, 2) void k_ffn2(
    const u16* __restrict__ A, const u16* __restrict__ B,
    const float* __restrict__ bias, void* __restrict__ Cout,
    int M, int N, int K, int sft) {
  __shared__ __align__(64) u16 lds[65536];
  gemm_body<0>(lds, A, B, bias, Cout, M, N, K, sft);
}

// ---------------------------------------------------------------------------
extern "C" void kernel_launch(void* const* d_in, const int* in_sizes, int n_in,
                              void* d_out, int out_size, void* d_ws,
                              size_t ws_size, hipStream_t stream) {
  const float* x  = (const float*)d_in[0];
  // d_in[1] = Wp, d_in[2] = bp : router is identity, unused.
  const float* W1 = (const float*)d_in[3];
  const float* b1 = (const float*)d_in[4];
  const float* W2 = (const float*)d_in[5];
  const float* b2 = (const float*)d_in[6];
  float* out = (float*)d_out;

  char* ws = (char*)d_ws;
  u16* Xb  = (u16*)(ws);                       // 8192x2048 bf16 = 32 MiB
  u16* W1T = (u16*)(ws + 33554432);            // 8192x2048 bf16 = 32 MiB
  u16* W2T = (u16*)(ws + 67108864);            // 2048x8192 bf16 = 32 MiB
  u16* H   = (u16*)(ws + 100663296);           // 8192x8192 bf16 = 128 MiB

  // 1. select + convert x
  k_convert_x<<<16384, 256, 0, stream>>>(x, Xb);
  // 2. transpose-convert weights
  k_transpose_bf16<<<dim3(8192 / 64, 2048 / 64), 256, 0, stream>>>(W1, W1T, 2048, 8192);
  k_transpose_bf16<<<dim3(2048 / 64, 8192 / 64), 256, 0, stream>>>(W2, W2T, 8192, 2048);
  // 3. H = gelu(Xb @ W1 + b1) : M=8192 N=8192 K=2048, 1024 blocks, cpx=4
  k_ffn1<<<1024, 512, 0, stream>>>(Xb, W1T, b1, (void*)H, 8192, 8192, 2048, 2);
  // 4. out = H @ W2 + b2      : M=8192 N=2048 K=8192, 256 blocks, cpx=1
  k_ffn2<<<256, 512, 0, stream>>>(H, W2T, b2, (void*)out, 8192, 2048, 8192, 0);
}

// Round 8
// 530.766 us; speedup vs baseline: 1.1269x; 1.0844x over previous
//
#include <hip/hip_runtime.h>
#include <hip/hip_bf16.h>

typedef unsigned int u32;
typedef unsigned short u16;

using bf16x8 = __attribute__((ext_vector_type(8))) short;
using f32x4  = __attribute__((ext_vector_type(4))) float;

#define DEVI static __device__ __forceinline__

DEVI u16 f2bf(float f) {
  __hip_bfloat16 h = __float2bfloat16(f);  // RNE
  union { __hip_bfloat16 h; u16 u; } v; v.h = h;
  return v.u;
}

// ---------------------------------------------------------------------------
// Kernel 1: select + convert x[:, :2048, :] (f32) -> Xb bf16 [8192][2048]
// Router is identity: softmax over size-1 axis == 1.0; top_k of equal scores
// returns indices 0..2047 (stable tie-break).
// ---------------------------------------------------------------------------
__global__ void k_convert_x(const float* __restrict__ x, u16* __restrict__ xb) {
  int idx = blockIdx.x * blockDim.x + threadIdx.x;   // 4 elems per thread
  size_t e = (size_t)idx * 4;
  int row = (int)(e >> 11);        // 0..8191
  int d   = (int)(e & 2047);
  int b = row >> 11, t = row & 2047;
  const float4 v = *reinterpret_cast<const float4*>(
      x + ((size_t)(b * 4096 + t) * 2048 + d));
  ushort4 o;
  o.x = f2bf(v.x); o.y = f2bf(v.y); o.z = f2bf(v.z); o.w = f2bf(v.w);
  *reinterpret_cast<ushort4*>(xb + (size_t)row * 2048 + d) = o;
}

// ---------------------------------------------------------------------------
// Kernel 2: transpose + convert  in[R][C] f32  ->  out[C][R] bf16
// ---------------------------------------------------------------------------
__global__ void k_transpose_bf16(const float* __restrict__ in,
                                 u16* __restrict__ out, int R, int C) {
  __shared__ u16 lds[64][66];
  const int t = threadIdx.x;        // 256
  const int tile_r = blockIdx.y * 64;
  const int tile_c = blockIdx.x * 64;
  const int cc = (t & 15) * 4;
  const int r0 = t >> 4;
#pragma unroll
  for (int i = 0; i < 4; ++i) {
    int r = r0 + i * 16;
    const float4 v = *reinterpret_cast<const float4*>(
        in + (size_t)(tile_r + r) * C + tile_c + cc);
    lds[r][cc]     = f2bf(v.x);
    lds[r][cc + 1] = f2bf(v.y);
    lds[r][cc + 2] = f2bf(v.z);
    lds[r][cc + 3] = f2bf(v.w);
  }
  __syncthreads();
  const int rr = (t & 15) * 4;
  const int c0 = t >> 4;
#pragma unroll
  for (int i = 0; i < 4; ++i) {
    int c = c0 + i * 16;
    ushort4 o;
    o.x = lds[rr][c]; o.y = lds[rr + 1][c];
    o.z = lds[rr + 2][c]; o.w = lds[rr + 3][c];
    *reinterpret_cast<ushort4*>(out + (size_t)(tile_c + c) * R + tile_r + rr) = o;
  }
}

// ---------------------------------------------------------------------------
// Kernel 3: 256x256 bf16 GEMM (16x16x32), 2-barrier overlap schedule:
//   per K-tile: issue ALL 24 ds_reads + 4 stage loads up front
//   (sched_barrier-pinned), then MFMA quadrants gated by the compiler's
//   counted lgkmcnt -> B1/A1 reads drain UNDER q00/q01's MFMAs.
//   Sync: lgkmcnt(0)+barrier mid-iter (all waves' reads from buf p done ->
//   restaging p is WAR-safe), counted vmcnt(4)+barrier publishes p^1.
//   T2 XOR swizzle (0 conflicts), T5 setprio, LDS-bounce epilogue.
// ---------------------------------------------------------------------------
#define GLDS16(g, l)                                                          \
  __builtin_amdgcn_global_load_lds(                                           \
      (const __attribute__((address_space(1))) u32*)(g),                      \
      (__attribute__((address_space(3))) u32*)(l), 16, 0, 0)

template <int DO_GELU, int BNPART>
DEVI void gemm_body(u16* lds, const u16* __restrict__ A,
                    const u16* __restrict__ B, const float* __restrict__ bias,
                    void* __restrict__ Cout, int M, int N, int K, int nbn,
                    int sft) {
  const int bid = blockIdx.x;
  int bm, bn;
  if (BNPART) {
    // XCD owns a bn-panel: per-XCD B working set <= 4 MB (L2-resident).
    const int local = bid >> 3;
    bn = ((bid & 7) << sft) + (local & ((1 << sft) - 1));
    bm = local >> sft;
  } else {
    // XCD owns a bm-chunk: per-XCD A working set L2-resident (ffn2).
    const int wg = (bid & 7) * (gridDim.x >> 3) + (bid >> 3);
    bm = wg / nbn; bn = wg % nbn;
  }

  const int tid  = threadIdx.x;
  const int w    = tid >> 6, lane = tid & 63;
  const int wr   = w >> 2, wcol = w & 3;   // wave tile: rows wr*128, cols wcol*64
  const int l15  = lane & 15, lhi = lane >> 4;

  const size_t arow0 = (size_t)bm * 256;
  const size_t brow0 = (size_t)bn * 256;

  // ---- staging: lane covers phys 16B chunk -> logical col chunk is XOR'd
  const int srow  = tid >> 3;                                  // 0..63
  const int scolb = ((tid & 7) * 16) ^ ((srow & 7) << 4);      // byte col in row
  const u16* pA = A + (arow0 + srow) * (size_t)K + (scolb >> 1);
  const u16* pB = B + (brow0 + srow) * (size_t)K + (scolb >> 1);
  const int wA = w * 512;  // u16 offset of this wave's 1KB stage slot

  // ---- fragment-read bases (bytes), swizzle folded in
  const u32 arow_b = (u32)((wr * 128 + l15) * 128);
  const u32 brow_b = (u32)((wcol * 64 + l15) * 128);
  const u32 axor   = (u32)((lhi * 16) ^ ((l15 & 7) << 4));
  const char* ldsb = (const char*)lds;

  f32x4 acc[8][4] = {};
  const int nk = K >> 6;

#define STAGE_PAIR(KT, PB, C)                                                 \
  do {                                                                        \
    GLDS16(pA + (size_t)(KT) * 64 + (size_t)(C) * 64 * (size_t)K,             \
           lds + (PB) * 16384 + (C) * 4096 + wA);                             \
    GLDS16(pB + (size_t)(KT) * 64 + (size_t)(C) * 64 * (size_t)K,             \
           lds + 32768 + (PB) * 16384 + (C) * 4096 + wA);                     \
  } while (0)

#define READ_A(DST, MH, ABASE)                                                \
  _Pragma("unroll") for (int m2 = 0; m2 < 4; ++m2)                            \
  _Pragma("unroll") for (int kk = 0; kk < 2; ++kk)                            \
    DST[m2][kk] = *(const bf16x8*)(ldsb + (ABASE) + arow_b +                  \
                                   ((MH)*4 + m2) * 2048 + (axor ^ (kk << 6)));

#define READ_B(DST, NH, BBASE)                                                \
  _Pragma("unroll") for (int n2 = 0; n2 < 2; ++n2)                            \
  _Pragma("unroll") for (int kk = 0; kk < 2; ++kk)                            \
    DST[n2][kk] = *(const bf16x8*)(ldsb + (BBASE) + brow_b +                  \
                                   ((NH)*2 + n2) * 2048 + (axor ^ (kk << 6)));

#define MFMA_Q(MH, NH, AREG, BREG)                                            \
  _Pragma("unroll") for (int m2 = 0; m2 < 4; ++m2)                            \
  _Pragma("unroll") for (int n2 = 0; n2 < 2; ++n2)                            \
  _Pragma("unroll") for (int kk = 0; kk < 2; ++kk)                            \
    acc[(MH)*4 + m2][(NH)*2 + n2] = __builtin_amdgcn_mfma_f32_16x16x32_bf16(  \
        AREG[m2][kk], BREG[n2][kk], acc[(MH)*4 + m2][(NH)*2 + n2], 0, 0, 0);

  // ---- prologue: kt0 fully staged; kt1 pairs 0,1 in flight.
  STAGE_PAIR(0, 0, 0); STAGE_PAIR(0, 0, 1);
  STAGE_PAIR(0, 0, 2); STAGE_PAIR(0, 0, 3);
  if (nk > 1) {
    STAGE_PAIR(1, 1, 0); STAGE_PAIR(1, 1, 1);
    asm volatile("s_waitcnt vmcnt(4)" ::: "memory");
  } else {
    asm volatile("s_waitcnt vmcnt(0)" ::: "memory");
  }
  __builtin_amdgcn_s_barrier();

  for (int kt = 0; kt < nk; ++kt) {
    const int p = kt & 1;
    const u32 abase = (u32)p * 32768u;            // bytes
    const u32 bbase = 65536u + (u32)p * 32768u;   // bytes
    bf16x8 a0[4][2], a1[4][2], b0[2][2], b1[2][2];

    // issue ALL reads (24) + remaining stage of kt+1 (4), pinned above MFMAs
    READ_A(a0, 0, abase);
    READ_B(b0, 0, bbase);
    READ_B(b1, 1, bbase);
    READ_A(a1, 1, abase);
    if (kt + 1 < nk) { STAGE_PAIR(kt + 1, p ^ 1, 2); STAGE_PAIR(kt + 1, p ^ 1, 3); }
    __builtin_amdgcn_sched_barrier(0);

    // q00/q01: compiler auto-gates on first 12/16 reads; A1 drains underneath
    __builtin_amdgcn_s_setprio(1);
    MFMA_Q(0, 0, a0, b0);
    MFMA_Q(0, 1, a0, b1);
    __builtin_amdgcn_s_setprio(0);

    // all my reads from buf p done; after barrier, every wave's are -> WAR-safe
    asm volatile("s_waitcnt lgkmcnt(0)" ::: "memory");
    __builtin_amdgcn_s_barrier();
    __builtin_amdgcn_sched_barrier(0);
    if (kt + 2 < nk) { STAGE_PAIR(kt + 2, p, 0); STAGE_PAIR(kt + 2, p, 1); }

    __builtin_amdgcn_s_setprio(1);
    MFMA_Q(1, 1, a1, b1);
    MFMA_Q(1, 0, a1, b0);
    __builtin_amdgcn_s_setprio(0);

    // publish p^1: kt+1's 8 loads complete (4 young kt+2 loads stay in flight)
    if (kt + 2 < nk) {
      asm volatile("s_waitcnt vmcnt(4)" ::: "memory");
    } else {
      asm volatile("s_waitcnt vmcnt(0)" ::: "memory");
    }
    __builtin_amdgcn_s_barrier();
  }

  // ---- epilogue: LDS-bounce to coalesced stores (main-loop LDS is dead).
  const int colb = (int)brow0 + wcol * 64;
  float bb[4];
#pragma unroll
  for (int n = 0; n < 4; ++n) bb[n] = bias[colb + n * 16 + l15];
  const int tr = lane >> 2, tc = (lane & 3) * 16;

  if (DO_GELU) {
    u16* slot = lds + (size_t)w * 1152;          // 16 x 72 u16
#pragma unroll
    for (int m = 0; m < 8; ++m) {
      const int rowb = (int)arow0 + wr * 128 + m * 16;
#pragma unroll
      for (int n = 0; n < 4; ++n)
#pragma unroll
        for (int r = 0; r < 4; ++r) {
          float v = acc[m][n][r] + bb[n];
          float u2 = v * (1.5957691216f + 0.0713548162f * v * v);
          float g  = v / (1.f + __expf(-u2));
          slot[(lhi * 4 + r) * 72 + n * 16 + l15] = f2bf(g);
        }
      asm volatile("s_waitcnt lgkmcnt(0)" ::: "memory");
      uint4 d0 = *(const uint4*)(slot + tr * 72 + tc);
      uint4 d1 = *(const uint4*)(slot + tr * 72 + tc + 8);
      u16* gp = (u16*)Cout + (size_t)(rowb + tr) * N + colb + tc;
      *(uint4*)gp = d0;
      *(uint4*)(gp + 8) = d1;
      asm volatile("s_waitcnt lgkmcnt(0)" ::: "memory");
    }
  } else {
    float* slotf = (float*)(void*)lds + (size_t)w * 1088;  // 16 x 68 f32
#pragma unroll
    for (int m = 0; m < 8; ++m) {
      const int rowb = (int)arow0 + wr * 128 + m * 16;
#pragma unroll
      for (int n = 0; n < 4; ++n)
#pragma unroll
        for (int r = 0; r < 4; ++r)
          slotf[(lhi * 4 + r) * 68 + n * 16 + l15] = acc[m][n][r] + bb[n];
      asm volatile("s_waitcnt lgkmcnt(0)" ::: "memory");
      float4 f0 = *(const float4*)(slotf + tr * 68 + tc);
      float4 f1 = *(const float4*)(slotf + tr * 68 + tc + 4);
      float4 f2 = *(const float4*)(slotf + tr * 68 + tc + 8);
      float4 f3 = *(const float4*)(slotf + tr * 68 + tc + 12);
      float* gp = (float*)Cout + (size_t)(rowb + tr) * N + colb + tc;
      *(float4*)gp = f0;
      *(float4*)(gp + 4) = f1;
      *(float4*)(gp + 8) = f2;
      *(float4*)(gp + 12) = f3;
      asm volatile("s_waitcnt lgkmcnt(0)" ::: "memory");
    }
  }
#undef STAGE_PAIR
#undef READ_A
#undef READ_B
#undef MFMA_Q
}

__global__ __launch_bounds__(512, 2) void k_ffn1(
    const u16* __restrict__ A, const u16* __restrict__ B,
    const float* __restrict__ bias, void* __restrict__ Cout,
    int M, int N, int K, int nbn, int sft) {
  __shared__ __align__(64) u16 lds[65536];
  gemm_body<1, 1>(lds, A, B, bias, Cout, M, N, K, nbn, sft);
}

__global__ __launch_bounds__(512, 2) void k_ffn2(
    const u16* __restrict__ A, const u16* __restrict__ B,
    const float* __restrict__ bias, void* __restrict__ Cout,
    int M, int N, int K, int nbn, int sft) {
  __shared__ __align__(64) u16 lds[65536];
  gemm_body<0, 0>(lds, A, B, bias, Cout, M, N, K, nbn, sft);
}

// ---------------------------------------------------------------------------
extern "C" void kernel_launch(void* const* d_in, const int* in_sizes, int n_in,
                              void* d_out, int out_size, void* d_ws,
                              size_t ws_size, hipStream_t stream) {
  const float* x  = (const float*)d_in[0];
  // d_in[1] = Wp, d_in[2] = bp : router is identity, unused.
  const float* W1 = (const float*)d_in[3];
  const float* b1 = (const float*)d_in[4];
  const float* W2 = (const float*)d_in[5];
  const float* b2 = (const float*)d_in[6];
  float* out = (float*)d_out;

  char* ws = (char*)d_ws;
  u16* Xb  = (u16*)(ws);                       // 8192x2048 bf16 = 32 MiB
  u16* W1T = (u16*)(ws + 33554432);            // 8192x2048 bf16 = 32 MiB
  u16* W2T = (u16*)(ws + 67108864);            // 2048x8192 bf16 = 32 MiB
  u16* H   = (u16*)(ws + 100663296);           // 8192x8192 bf16 = 128 MiB

  // 1. select + convert x
  k_convert_x<<<16384, 256, 0, stream>>>(x, Xb);
  // 2. transpose-convert weights
  k_transpose_bf16<<<dim3(8192 / 64, 2048 / 64), 256, 0, stream>>>(W1, W1T, 2048, 8192);
  k_transpose_bf16<<<dim3(2048 / 64, 8192 / 64), 256, 0, stream>>>(W2, W2T, 8192, 2048);
  // 3. H = gelu(Xb @ W1 + b1) : M=8192 N=8192 K=2048, 1024 blocks, bn-panel
  k_ffn1<<<1024, 512, 0, stream>>>(Xb, W1T, b1, (void*)H, 8192, 8192, 2048, 32, 2);
  // 4. out = H @ W2 + b2      : M=8192 N=2048 K=8192, 256 blocks, bm-chunk
  k_ffn2<<<256, 512, 0, stream>>>(H, W2T, b2, (void*)out, 8192, 2048, 8192, 8, 0);
}